// Round 5
// baseline (790.777 us; speedup 1.0000x reference)
//
#include <hip/hip_runtime.h>
#include <hip/hip_bf16.h>

// GCN (bf16 pipeline): z1 = prelu(Agg(xb@W1)+b1); z2 = prelu(Agg(z1@W2)+b2)
// z = BN(z2) [f32 out + bf16 copy]; p = prelu(BN2(z@projW)) [proj_b cancels in BN]
// out = [z | p] (f32)
//
// Graph build: binned 2-phase CSR (k_bin -> k_csr) to avoid 1.6M scattered
// 4B line-dirtying writes (R2: k_fill WRITE_SIZE 99MB for 6.4MB payload).

#define CAP 96          // max in-degree capacity (actual max deg ~58)
#define NPB 128         // nodes per bucket
#define NPART 8         // partitions (blockIdx&7 ~ XCD locality heuristic)
#define SEGCAP 768      // entries per (bucket,partition) segment; avg ~512

typedef __attribute__((ext_vector_type(8))) short short8;
typedef __attribute__((ext_vector_type(4))) float f32x4;

__device__ __forceinline__ float bf2f(unsigned short u) {
    union { unsigned int i; float f; } v; v.i = ((unsigned int)u) << 16; return v.f;
}
__device__ __forceinline__ unsigned short f2bf(float f) {
    __hip_bfloat16 h = __float2bfloat16(f);   // RNE
    return *reinterpret_cast<unsigned short*>(&h);
}

// ---------------- zero: segcnt, stats, dinv[N] sentinel ----------------
__global__ __launch_bounds__(256) void k_zero(int* segcnt, int nseg, float* stats, float* dinv, int N) {
    int i = blockIdx.x * 256 + threadIdx.x;
    if (i < nseg) segcnt[i] = 0;
    if (i < 2048) stats[i] = 0.0f;
    if (i == 0) dinv[N] = 0.0f;   // padding sentinel weight
}

// ---------------- phase 1: bin edges by destination bucket ----------------
__global__ __launch_bounds__(256) void k_bin(const int* __restrict__ row, const int* __restrict__ col,
                                             unsigned* __restrict__ bins, int* __restrict__ segcnt, int E) {
    int e = blockIdx.x * 256 + threadIdx.x;
    if (e >= E) return;
    int v = col[e];
    int r = row[e];                       // r < 65536 fits 16 bits; pack (r<<7)|loc
    int seg = (v >> 7) * NPART + (blockIdx.x & (NPART - 1));
    int p = atomicAdd(&segcnt[seg], 1);
    if (p < SEGCAP) bins[(size_t)seg * SEGCAP + p] = ((unsigned)r << 7) | (unsigned)(v & (NPB - 1));
}

// ---------------- phase 2: per-bucket CSR scatter + dinv + pad-to-8 ----------------
__global__ __launch_bounds__(256) void k_csr(const unsigned* __restrict__ bins, const int* __restrict__ segcnt,
                                             int* __restrict__ csr, int* __restrict__ fillp,
                                             float* __restrict__ dinv, int N) {
    __shared__ int cnt[NPB];
    int bkt = blockIdx.x;
    if (threadIdx.x < NPB) cnt[threadIdx.x] = 0;
    __syncthreads();
    for (int part = 0; part < NPART; ++part) {
        int seg = bkt * NPART + part;
        int m = segcnt[seg]; if (m > SEGCAP) m = SEGCAP;
        const unsigned* b = bins + (size_t)seg * SEGCAP;
        for (int i = threadIdx.x; i < m; i += 256) {
            unsigned ent = b[i];
            int loc = (int)(ent & (NPB - 1));
            int r   = (int)(ent >> 7);
            int p = atomicAdd(&cnt[loc], 1);
            if (p < CAP) csr[(size_t)(bkt * NPB + loc) * CAP + p] = r;
        }
    }
    __syncthreads();
    if (threadIdx.x < NPB) {
        int v = bkt * NPB + threadIdx.x;
        if (v < N) {
            int c = cnt[threadIdx.x];
            int real = c < CAP ? c : CAP;
            int pc = (real + 7) & ~7;             // pad to multiple of 8
            if (pc > CAP) pc = CAP;               // (deg>=89 impossible in practice)
            int* lst = csr + (size_t)v * CAP;
            for (int p = real; p < pc; ++p) lst[p] = N;   // sentinel: dinv[N]=0
            fillp[v] = pc;
            dinv[v] = rsqrtf(1.0f + (float)c);    // +1 self loop
        }
    }
}

// ---------------- cast f32 -> bf16 (vectorized) ----------------
__global__ __launch_bounds__(256) void k_castx(const float* __restrict__ x, unsigned short* __restrict__ xb, size_t n4) {
    size_t stride = (size_t)gridDim.x * blockDim.x;
    for (size_t i = (size_t)blockIdx.x * blockDim.x + threadIdx.x; i < n4; i += stride) {
        float4 v = ((const float4*)x)[i];
        ushort4 o; o.x = f2bf(v.x); o.y = f2bf(v.y); o.z = f2bf(v.z); o.w = f2bf(v.w);
        ((ushort4*)xb)[i] = o;
    }
}

// ---------------- W [256,256] f32 -> Wt [n][k] bf16 (transpose + cast) ----------------
__global__ __launch_bounds__(256) void k_wt(const float* __restrict__ W, unsigned short* __restrict__ Wt) {
    __shared__ float t[32][33];
    int bx = blockIdx.x * 32, by = blockIdx.y * 32;
    int x = threadIdx.x & 31, y = threadIdx.x >> 5;   // 32x8
#pragma unroll
    for (int i = 0; i < 32; i += 8)
        t[y + i][x] = W[(size_t)(by + y + i) * 256 + bx + x];
    __syncthreads();
#pragma unroll
    for (int i = 0; i < 32; i += 8)
        Wt[(size_t)(bx + y + i) * 256 + by + x] = f2bf(t[x][y + i]);  // Wt[n][k] = W[k][n]
}

// ---------------- bf16 MFMA GEMM: C[M,256] = A[M,256] @ B ; B given as Bt[n][k] ----------------
__global__ __launch_bounds__(256) void k_gemm_bf16(const unsigned short* __restrict__ A,
                                                   const unsigned short* __restrict__ Bt,
                                                   unsigned short* __restrict__ C, int M) {
    __shared__ unsigned short As[128 * 64];   // [row][k] linear
    __shared__ unsigned short Bs[128 * 64];   // [col][k] linear
    int tid  = threadIdx.x;
    int lane = tid & 63, wid = tid >> 6;
    int wr = wid >> 1, wc = wid & 1;
    int row0 = blockIdx.x * 128;
    int col0 = blockIdx.y * 128;

    f32x4 acc[4][4];
#pragma unroll
    for (int m = 0; m < 4; ++m)
#pragma unroll
        for (int n = 0; n < 4; ++n) acc[m][n] = f32x4{0.f, 0.f, 0.f, 0.f};

    int srow = lane >> 3;          // 0..7
    int sk   = (lane & 7) * 8;     // 0,8,...,56

    for (int k0 = 0; k0 < 256; k0 += 64) {
#pragma unroll
        for (int i = 0; i < 4; ++i) {
            int u = i * 4 + wid;                       // load unit 0..15, wave-uniform
            int arow = row0 + u * 8 + srow;
            if (arow >= M) arow = M - 1;               // per-lane source clamp (dest stays linear)
            const unsigned short* ga = A  + (size_t)arow * 256 + k0 + sk;
            const unsigned short* gb = Bt + (size_t)(col0 + u * 8 + srow) * 256 + k0 + sk;
            __builtin_amdgcn_global_load_lds((const __attribute__((address_space(1))) void*)ga,
                (__attribute__((address_space(3))) void*)(As + u * 512), 16, 0, 0);
            __builtin_amdgcn_global_load_lds((const __attribute__((address_space(1))) void*)gb,
                (__attribute__((address_space(3))) void*)(Bs + u * 512), 16, 0, 0);
        }
        __syncthreads();
#pragma unroll
        for (int kk = 0; kk < 64; kk += 32) {
            short8 a[4], b[4];
#pragma unroll
            for (int m = 0; m < 4; ++m)
                a[m] = *(const short8*)(As + (wr * 64 + m * 16 + (lane & 15)) * 64 + kk + (lane >> 4) * 8);
#pragma unroll
            for (int n = 0; n < 4; ++n)
                b[n] = *(const short8*)(Bs + (wc * 64 + n * 16 + (lane & 15)) * 64 + kk + (lane >> 4) * 8);
#pragma unroll
            for (int m = 0; m < 4; ++m)
#pragma unroll
                for (int n = 0; n < 4; ++n)
                    acc[m][n] = __builtin_amdgcn_mfma_f32_16x16x32_bf16(a[m], b[n], acc[m][n], 0, 0, 0);
        }
        __syncthreads();
    }

    int crow = row0 + wr * 64;
    int ccol = col0 + wc * 64;
#pragma unroll
    for (int m = 0; m < 4; ++m)
#pragma unroll
        for (int r = 0; r < 4; ++r) {
            int rr = crow + m * 16 + (lane >> 4) * 4 + r;
            if (rr < M) {
#pragma unroll
                for (int n = 0; n < 4; ++n)
                    C[(size_t)rr * 256 + ccol + n * 16 + (lane & 15)] = f2bf(acc[m][n][r]);
            }
        }
}

// ---------------- aggregation (bf16): pure 8-wide (padded lists) ----------------
__global__ __launch_bounds__(256) void k_agg_bf(const unsigned short* __restrict__ h,
                                                unsigned short* __restrict__ outb,
                                                const float* __restrict__ dinv, const int* __restrict__ csr,
                                                const int* __restrict__ fillp, const float* __restrict__ bias,
                                                const float* __restrict__ aptr, int N) {
    int wv = threadIdx.x >> 6, lane = threadIdx.x & 63;   // one node per wave, 4 ch/lane
    int v = blockIdx.x * 4 + wv;
    if (v >= N) return;
    const ushort4* h4 = (const ushort4*)h;
    float dv = dinv[v];
    ushort4 hv = h4[(size_t)v * 64 + lane];
    float s0 = dv * bf2f(hv.x), s1 = dv * bf2f(hv.y), s2 = dv * bf2f(hv.z), s3 = dv * bf2f(hv.w);
    int n = fillp[v];                      // multiple of 8 (sentinel-padded)
    const int* lst = csr + (size_t)v * CAP;
    for (int i = 0; i < n; i += 8) {
        int u0 = lst[i],     u1 = lst[i + 1], u2 = lst[i + 2], u3 = lst[i + 3];
        int u4 = lst[i + 4], u5 = lst[i + 5], u6 = lst[i + 6], u7 = lst[i + 7];
        ushort4 a0 = h4[(size_t)u0 * 64 + lane];
        ushort4 a1 = h4[(size_t)u1 * 64 + lane];
        ushort4 a2 = h4[(size_t)u2 * 64 + lane];
        ushort4 a3 = h4[(size_t)u3 * 64 + lane];
        ushort4 a4 = h4[(size_t)u4 * 64 + lane];
        ushort4 a5 = h4[(size_t)u5 * 64 + lane];
        ushort4 a6 = h4[(size_t)u6 * 64 + lane];
        ushort4 a7 = h4[(size_t)u7 * 64 + lane];
        float d0 = dinv[u0], d1 = dinv[u1], d2 = dinv[u2], d3 = dinv[u3];
        float d4 = dinv[u4], d5 = dinv[u5], d6 = dinv[u6], d7 = dinv[u7];
        s0 += d0 * bf2f(a0.x) + d1 * bf2f(a1.x) + d2 * bf2f(a2.x) + d3 * bf2f(a3.x)
            + d4 * bf2f(a4.x) + d5 * bf2f(a5.x) + d6 * bf2f(a6.x) + d7 * bf2f(a7.x);
        s1 += d0 * bf2f(a0.y) + d1 * bf2f(a1.y) + d2 * bf2f(a2.y) + d3 * bf2f(a3.y)
            + d4 * bf2f(a4.y) + d5 * bf2f(a5.y) + d6 * bf2f(a6.y) + d7 * bf2f(a7.y);
        s2 += d0 * bf2f(a0.z) + d1 * bf2f(a1.z) + d2 * bf2f(a2.z) + d3 * bf2f(a3.z)
            + d4 * bf2f(a4.z) + d5 * bf2f(a5.z) + d6 * bf2f(a6.z) + d7 * bf2f(a7.z);
        s3 += d0 * bf2f(a0.w) + d1 * bf2f(a1.w) + d2 * bf2f(a2.w) + d3 * bf2f(a3.w)
            + d4 * bf2f(a4.w) + d5 * bf2f(a5.w) + d6 * bf2f(a6.w) + d7 * bf2f(a7.w);
    }
    float a = *aptr;
    float4 bb = *(const float4*)(bias + lane * 4);
    float o0 = dv * s0 + bb.x, o1 = dv * s1 + bb.y, o2 = dv * s2 + bb.z, o3 = dv * s3 + bb.w;
    o0 = o0 >= 0.f ? o0 : a * o0;
    o1 = o1 >= 0.f ? o1 : a * o1;
    o2 = o2 >= 0.f ? o2 : a * o2;
    o3 = o3 >= 0.f ? o3 : a * o3;
    ushort4 o; o.x = f2bf(o0); o.y = f2bf(o1); o.z = f2bf(o2); o.w = f2bf(o3);
    ((ushort4*)outb)[(size_t)v * 64 + lane] = o;
}

// ---------------- BN column stats (vectorized ushort4) ----------------
__global__ __launch_bounds__(256) void k_bnstats_v(const unsigned short* __restrict__ X, float* __restrict__ sums, int N) {
    int w = threadIdx.x >> 6, lane = threadIdx.x & 63;
    int c4 = lane * 4;
    float4 s = {0.f, 0.f, 0.f, 0.f}, q = {0.f, 0.f, 0.f, 0.f};
    int rstride = gridDim.x * 4;
    for (int r = blockIdx.x * 4 + w; r < N; r += rstride) {
        ushort4 x4 = ((const ushort4*)X)[(size_t)r * 64 + lane];
        float a = bf2f(x4.x), b = bf2f(x4.y), c = bf2f(x4.z), d = bf2f(x4.w);
        s.x += a; s.y += b; s.z += c; s.w += d;
        q.x += a * a; q.y += b * b; q.z += c * c; q.w += d * d;
    }
    atomicAdd(&sums[c4 + 0], s.x); atomicAdd(&sums[c4 + 1], s.y);
    atomicAdd(&sums[c4 + 2], s.z); atomicAdd(&sums[c4 + 3], s.w);
    atomicAdd(&sums[256 + c4 + 0], q.x); atomicAdd(&sums[256 + c4 + 1], q.y);
    atomicAdd(&sums[256 + c4 + 2], q.z); atomicAdd(&sums[256 + c4 + 3], q.w);
}

__global__ __launch_bounds__(256) void k_bnfinal(float* stats, const float* __restrict__ gamma,
                                                 const float* __restrict__ beta, float invN) {
    int c = threadIdx.x;
    float mu = stats[c] * invN;
    float var = stats[256 + c] * invN - mu * mu;
    float rstd = rsqrtf(var + 1e-5f);
    float sc = rstd * gamma[c];
    stats[512 + c] = sc;
    stats[768 + c] = beta[c] - mu * sc;
}

// ---------------- BN apply for z: f32 out + bf16 copy (no prelu) ----------------
__global__ __launch_bounds__(256) void k_bnapply_z(const unsigned short* __restrict__ in,
                                                   float* __restrict__ zout, unsigned short* __restrict__ zb,
                                                   const float* __restrict__ scale, const float* __restrict__ shift,
                                                   size_t n4) {
    size_t stride = (size_t)gridDim.x * blockDim.x;
    for (size_t i = (size_t)blockIdx.x * blockDim.x + threadIdx.x; i < n4; i += stride) {
        int c4 = (int)(i & 63) * 4;
        ushort4 x4 = ((const ushort4*)in)[i];
        float4 sc = *(const float4*)(scale + c4);
        float4 sh = *(const float4*)(shift + c4);
        float4 y;
        y.x = bf2f(x4.x) * sc.x + sh.x;
        y.y = bf2f(x4.y) * sc.y + sh.y;
        y.z = bf2f(x4.z) * sc.z + sh.z;
        y.w = bf2f(x4.w) * sc.w + sh.w;
        ((float4*)zout)[i] = y;
        ushort4 o; o.x = f2bf(y.x); o.y = f2bf(y.y); o.z = f2bf(y.z); o.w = f2bf(y.w);
        ((ushort4*)zb)[i] = o;
    }
}

// ---------------- BN apply for p: prelu, f32 out ----------------
__global__ __launch_bounds__(256) void k_bnapply_p(const unsigned short* __restrict__ in,
                                                   float* __restrict__ pout,
                                                   const float* __restrict__ scale, const float* __restrict__ shift,
                                                   const float* __restrict__ aptr, size_t n4) {
    size_t stride = (size_t)gridDim.x * blockDim.x;
    float a = *aptr;
    for (size_t i = (size_t)blockIdx.x * blockDim.x + threadIdx.x; i < n4; i += stride) {
        int c4 = (int)(i & 63) * 4;
        ushort4 x4 = ((const ushort4*)in)[i];
        float4 sc = *(const float4*)(scale + c4);
        float4 sh = *(const float4*)(shift + c4);
        float4 y;
        y.x = bf2f(x4.x) * sc.x + sh.x;
        y.y = bf2f(x4.y) * sc.y + sh.y;
        y.z = bf2f(x4.z) * sc.z + sh.z;
        y.w = bf2f(x4.w) * sc.w + sh.w;
        y.x = y.x >= 0.f ? y.x : a * y.x;
        y.y = y.y >= 0.f ? y.y : a * y.y;
        y.z = y.z >= 0.f ? y.z : a * y.z;
        y.w = y.w >= 0.f ? y.w : a * y.w;
        ((float4*)pout)[i] = y;
    }
}

extern "C" void kernel_launch(void* const* d_in, const int* in_sizes, int n_in,
                              void* d_out, int out_size, void* d_ws, size_t ws_size,
                              hipStream_t stream) {
    const float* x     = (const float*)d_in[0];
    const int*   ei    = (const int*)d_in[1];
    const float* W1    = (const float*)d_in[2];
    const float* b1    = (const float*)d_in[3];
    const float* W2    = (const float*)d_in[4];
    const float* b2    = (const float*)d_in[5];
    const float* aptr  = (const float*)d_in[6];
    const float* gamma = (const float*)d_in[7];
    const float* beta  = (const float*)d_in[8];
    const float* projW = (const float*)d_in[9];
    // d_in[10] = proj_b: cancels inside BN, unused
    const float* pgamma = (const float*)d_in[11];
    const float* pbeta  = (const float*)d_in[12];
    const float* a2ptr  = (const float*)d_in[13];

    int N = in_sizes[0] / 256;
    int E = in_sizes[1] / 2;
    const int* row = ei;
    const int* col = ei + E;

    float* out  = (float*)d_out;
    float* zout = out;
    float* pout = out + (size_t)N * 256;

    int nbkt = (N + NPB - 1) / NPB;
    int nseg = nbkt * NPART;

    // workspace layout (~96.8 MB): B0|B1|B2 bf16 [N,256], Wt, dinv[N+1], fillp, csr, stats, segcnt
    unsigned short* B0 = (unsigned short*)d_ws;
    unsigned short* B1 = B0 + (size_t)N * 256;
    unsigned short* B2 = B1 + (size_t)N * 256;
    unsigned short* Wt = B2 + (size_t)N * 256;
    float* dinv  = (float*)(Wt + 3 * 65536);
    int*   fillp = (int*)(dinv + N + 1);
    int*   csr   = fillp + N;
    float* stats = (float*)(csr + (size_t)N * CAP);
    int*   segcnt= (int*)(stats + 2048);
    unsigned* bins = (unsigned*)B1;    // alias: bins (9.6MB) dead before gemm1 writes B1

    int nb_E = (E + 255) / 256;
    dim3 ggrid((N + 127) / 128, 2);
    dim3 wgrid(8, 8);
    int  agrid = (N + 3) / 4;
    size_t n4 = (size_t)N * 64;

    // graph build + precasts
    k_zero <<<(nseg + 2303) / 256, 256, 0, stream>>>(segcnt, nseg, stats, dinv, N);
    k_bin  <<<nb_E, 256, 0, stream>>>(row, col, bins, segcnt, E);
    k_csr  <<<nbkt, 256, 0, stream>>>(bins, segcnt, csr, fillp, dinv, N);
    k_castx<<<2048, 256, 0, stream>>>(x, B0, n4);
    k_wt   <<<wgrid, 256, 0, stream>>>(W1,    Wt);
    k_wt   <<<wgrid, 256, 0, stream>>>(W2,    Wt + 65536);
    k_wt   <<<wgrid, 256, 0, stream>>>(projW, Wt + 131072);

    // layer 1
    k_gemm_bf16<<<ggrid, 256, 0, stream>>>(B0, Wt, B1, N);
    k_agg_bf   <<<agrid, 256, 0, stream>>>(B1, B2, dinv, csr, fillp, b1, aptr, N);
    // layer 2
    k_gemm_bf16<<<ggrid, 256, 0, stream>>>(B2, Wt + 65536, B1, N);
    k_agg_bf   <<<agrid, 256, 0, stream>>>(B1, B0, dinv, csr, fillp, b2, aptr, N);
    // BN(z2) -> z (f32) + zb (bf16)
    k_bnstats_v<<<128, 256, 0, stream>>>(B0, stats, N);
    k_bnfinal  <<<1, 256, 0, stream>>>(stats, gamma, beta, 1.0f / (float)N);
    k_bnapply_z<<<2048, 256, 0, stream>>>(B0, zout, B2, stats + 512, stats + 768, n4);
    // projection head
    k_gemm_bf16<<<ggrid, 256, 0, stream>>>(B2, Wt + 131072, B1, N);
    k_bnstats_v<<<128, 256, 0, stream>>>(B1, stats + 1024, N);
    k_bnfinal  <<<1, 256, 0, stream>>>(stats + 1024, pgamma, pbeta, 1.0f / (float)N);
    k_bnapply_p<<<2048, 256, 0, stream>>>(B1, pout, stats + 1536, stats + 1792, a2ptr, n4);
}

// Round 6
// 682.401 us; speedup vs baseline: 1.1588x; 1.1588x over previous
//
#include <hip/hip_runtime.h>
#include <hip/hip_bf16.h>

// GCN (bf16 pipeline): z1 = prelu(Agg(xb@W1)+b1); z2 = prelu(Agg(z1@W2)+b2)
// z = BN(z2) [f32 out + bf16 copy]; p = prelu(BN2(z@projW)) [proj_b cancels in BN]
// out = [z | p] (f32)
//
// Graph build evolution:
//  R2 k_fill: 1 global atomic + scattered 4B write per edge -> 128us (WRITE 99MB)
//  R5 k_bin:  same atomic count, fewer counters -> 150us (atomic ceiling ~10G/s)
//  R6 k_binh: LDS histogram per 4096-edge chunk; ~153K global atomics total
//             (one per block x nonempty bucket); contiguous segment writes.

#define CAP 96          // max in-degree capacity (actual max deg ~60)
#define NPB 128         // nodes per bucket
#define CHUNK 4096      // edges per k_binh block
#define SEGBIG 4608     // entries per bucket segment (mean 4096 + 8 sigma)
#define MAXBKT 512      // supports N up to 65536

typedef __attribute__((ext_vector_type(8))) short short8;
typedef __attribute__((ext_vector_type(4))) float f32x4;

__device__ __forceinline__ float bf2f(unsigned short u) {
    union { unsigned int i; float f; } v; v.i = ((unsigned int)u) << 16; return v.f;
}
__device__ __forceinline__ unsigned short f2bf(float f) {
    __hip_bfloat16 h = __float2bfloat16(f);   // RNE
    return *reinterpret_cast<unsigned short*>(&h);
}

// ---------------- zero: segcnt, stats, dinv[N] sentinel ----------------
__global__ __launch_bounds__(256) void k_zero(int* segcnt, int nbkt, float* stats, float* dinv, int N) {
    int i = blockIdx.x * 256 + threadIdx.x;
    if (i < nbkt) segcnt[i] = 0;
    if (i < 2048) stats[i] = 0.0f;
    if (i == 0) dinv[N] = 0.0f;   // padding sentinel weight
}

// ---------------- phase 1: LDS-histogram binning by destination bucket ----------------
__global__ __launch_bounds__(256) void k_binh(const int* __restrict__ row, const int* __restrict__ col,
                                              unsigned* __restrict__ bins, int* __restrict__ segcnt,
                                              int E, int nbkt) {
    __shared__ int hist[MAXBKT];
    __shared__ int base[MAXBKT];
    int e0 = blockIdx.x * CHUNK;
    int eend = e0 + CHUNK; if (eend > E) eend = E;
    for (int b = threadIdx.x; b < nbkt; b += 256) hist[b] = 0;
    __syncthreads();
    // pass A: count per bucket (LDS atomics)
    for (int e = e0 + threadIdx.x; e < eend; e += 256)
        atomicAdd(&hist[col[e] >> 7], 1);
    __syncthreads();
    // reserve contiguous ranges: one global atomic per nonempty bucket
    for (int b = threadIdx.x; b < nbkt; b += 256) {
        int h = hist[b];
        base[b] = h ? atomicAdd(&segcnt[b], h) : 0;
        hist[b] = 0;                       // reuse as running offset
    }
    __syncthreads();
    // pass B: place entries contiguously in reserved range (edges re-read from L2)
    for (int e = e0 + threadIdx.x; e < eend; e += 256) {
        int v = col[e], r = row[e];
        int b = v >> 7;
        int p = base[b] + atomicAdd(&hist[b], 1);
        if (p < SEGBIG) bins[(size_t)b * SEGBIG + p] = ((unsigned)r << 7) | (unsigned)(v & (NPB - 1));
    }
}

// ---------------- phase 2: per-bucket CSR scatter + dinv + pad-to-8 ----------------
__global__ __launch_bounds__(256) void k_csr(const unsigned* __restrict__ bins, const int* __restrict__ segcnt,
                                             int* __restrict__ csr, int* __restrict__ fillp,
                                             float* __restrict__ dinv, int N) {
    __shared__ int cnt[NPB];
    int bkt = blockIdx.x;
    if (threadIdx.x < NPB) cnt[threadIdx.x] = 0;
    __syncthreads();
    int m = segcnt[bkt]; if (m > SEGBIG) m = SEGBIG;
    const unsigned* b = bins + (size_t)bkt * SEGBIG;
    for (int i = threadIdx.x; i < m; i += 256) {
        unsigned ent = b[i];
        int loc = (int)(ent & (NPB - 1));
        int r   = (int)(ent >> 7);
        int p = atomicAdd(&cnt[loc], 1);
        if (p < CAP) csr[(size_t)(bkt * NPB + loc) * CAP + p] = r;
    }
    __syncthreads();
    if (threadIdx.x < NPB) {
        int v = bkt * NPB + threadIdx.x;
        if (v < N) {
            int c = cnt[threadIdx.x];
            int real = c < CAP ? c : CAP;
            int pc = (real + 7) & ~7;             // pad to multiple of 8
            if (pc > CAP) pc = CAP;
            int* lst = csr + (size_t)v * CAP;
            for (int p = real; p < pc; ++p) lst[p] = N;   // sentinel: dinv[N]=0
            fillp[v] = pc;
            dinv[v] = rsqrtf(1.0f + (float)c);    // +1 self loop
        }
    }
}

// ---------------- cast f32 -> bf16 (vectorized) ----------------
__global__ __launch_bounds__(256) void k_castx(const float* __restrict__ x, unsigned short* __restrict__ xb, size_t n4) {
    size_t stride = (size_t)gridDim.x * blockDim.x;
    for (size_t i = (size_t)blockIdx.x * blockDim.x + threadIdx.x; i < n4; i += stride) {
        float4 v = ((const float4*)x)[i];
        ushort4 o; o.x = f2bf(v.x); o.y = f2bf(v.y); o.z = f2bf(v.z); o.w = f2bf(v.w);
        ((ushort4*)xb)[i] = o;
    }
}

// ---------------- W [256,256] f32 -> Wt [n][k] bf16 (transpose + cast) ----------------
__global__ __launch_bounds__(256) void k_wt(const float* __restrict__ W, unsigned short* __restrict__ Wt) {
    __shared__ float t[32][33];
    int bx = blockIdx.x * 32, by = blockIdx.y * 32;
    int x = threadIdx.x & 31, y = threadIdx.x >> 5;   // 32x8
#pragma unroll
    for (int i = 0; i < 32; i += 8)
        t[y + i][x] = W[(size_t)(by + y + i) * 256 + bx + x];
    __syncthreads();
#pragma unroll
    for (int i = 0; i < 32; i += 8)
        Wt[(size_t)(bx + y + i) * 256 + by + x] = f2bf(t[x][y + i]);  // Wt[n][k] = W[k][n]
}

// ---------------- bf16 MFMA GEMM: C[M,256] = A[M,256] @ B ; B given as Bt[n][k] ----------------
__global__ __launch_bounds__(256) void k_gemm_bf16(const unsigned short* __restrict__ A,
                                                   const unsigned short* __restrict__ Bt,
                                                   unsigned short* __restrict__ C, int M) {
    __shared__ unsigned short As[128 * 64];   // [row][k] linear
    __shared__ unsigned short Bs[128 * 64];   // [col][k] linear
    int tid  = threadIdx.x;
    int lane = tid & 63, wid = tid >> 6;
    int wr = wid >> 1, wc = wid & 1;
    int row0 = blockIdx.x * 128;
    int col0 = blockIdx.y * 128;

    f32x4 acc[4][4];
#pragma unroll
    for (int m = 0; m < 4; ++m)
#pragma unroll
        for (int n = 0; n < 4; ++n) acc[m][n] = f32x4{0.f, 0.f, 0.f, 0.f};

    int srow = lane >> 3;          // 0..7
    int sk   = (lane & 7) * 8;     // 0,8,...,56

    for (int k0 = 0; k0 < 256; k0 += 64) {
#pragma unroll
        for (int i = 0; i < 4; ++i) {
            int u = i * 4 + wid;                       // load unit 0..15, wave-uniform
            int arow = row0 + u * 8 + srow;
            if (arow >= M) arow = M - 1;               // per-lane source clamp (dest stays linear)
            const unsigned short* ga = A  + (size_t)arow * 256 + k0 + sk;
            const unsigned short* gb = Bt + (size_t)(col0 + u * 8 + srow) * 256 + k0 + sk;
            __builtin_amdgcn_global_load_lds((const __attribute__((address_space(1))) void*)ga,
                (__attribute__((address_space(3))) void*)(As + u * 512), 16, 0, 0);
            __builtin_amdgcn_global_load_lds((const __attribute__((address_space(1))) void*)gb,
                (__attribute__((address_space(3))) void*)(Bs + u * 512), 16, 0, 0);
        }
        __syncthreads();
#pragma unroll
        for (int kk = 0; kk < 64; kk += 32) {
            short8 a[4], b[4];
#pragma unroll
            for (int m = 0; m < 4; ++m)
                a[m] = *(const short8*)(As + (wr * 64 + m * 16 + (lane & 15)) * 64 + kk + (lane >> 4) * 8);
#pragma unroll
            for (int n = 0; n < 4; ++n)
                b[n] = *(const short8*)(Bs + (wc * 64 + n * 16 + (lane & 15)) * 64 + kk + (lane >> 4) * 8);
#pragma unroll
            for (int m = 0; m < 4; ++m)
#pragma unroll
                for (int n = 0; n < 4; ++n)
                    acc[m][n] = __builtin_amdgcn_mfma_f32_16x16x32_bf16(a[m], b[n], acc[m][n], 0, 0, 0);
        }
        __syncthreads();
    }

    int crow = row0 + wr * 64;
    int ccol = col0 + wc * 64;
#pragma unroll
    for (int m = 0; m < 4; ++m)
#pragma unroll
        for (int r = 0; r < 4; ++r) {
            int rr = crow + m * 16 + (lane >> 4) * 4 + r;
            if (rr < M) {
#pragma unroll
                for (int n = 0; n < 4; ++n)
                    C[(size_t)rr * 256 + ccol + n * 16 + (lane & 15)] = f2bf(acc[m][n][r]);
            }
        }
}

// ---------------- aggregation (bf16): pure 8-wide (padded lists) ----------------
__global__ __launch_bounds__(256) void k_agg_bf(const unsigned short* __restrict__ h,
                                                unsigned short* __restrict__ outb,
                                                const float* __restrict__ dinv, const int* __restrict__ csr,
                                                const int* __restrict__ fillp, const float* __restrict__ bias,
                                                const float* __restrict__ aptr, int N) {
    int wv = threadIdx.x >> 6, lane = threadIdx.x & 63;   // one node per wave, 4 ch/lane
    int v = blockIdx.x * 4 + wv;
    if (v >= N) return;
    const ushort4* h4 = (const ushort4*)h;
    float dv = dinv[v];
    ushort4 hv = h4[(size_t)v * 64 + lane];
    float s0 = dv * bf2f(hv.x), s1 = dv * bf2f(hv.y), s2 = dv * bf2f(hv.z), s3 = dv * bf2f(hv.w);
    int n = fillp[v];                      // multiple of 8 (sentinel-padded)
    const int* lst = csr + (size_t)v * CAP;
    for (int i = 0; i < n; i += 8) {
        int u0 = lst[i],     u1 = lst[i + 1], u2 = lst[i + 2], u3 = lst[i + 3];
        int u4 = lst[i + 4], u5 = lst[i + 5], u6 = lst[i + 6], u7 = lst[i + 7];
        ushort4 a0 = h4[(size_t)u0 * 64 + lane];
        ushort4 a1 = h4[(size_t)u1 * 64 + lane];
        ushort4 a2 = h4[(size_t)u2 * 64 + lane];
        ushort4 a3 = h4[(size_t)u3 * 64 + lane];
        ushort4 a4 = h4[(size_t)u4 * 64 + lane];
        ushort4 a5 = h4[(size_t)u5 * 64 + lane];
        ushort4 a6 = h4[(size_t)u6 * 64 + lane];
        ushort4 a7 = h4[(size_t)u7 * 64 + lane];
        float d0 = dinv[u0], d1 = dinv[u1], d2 = dinv[u2], d3 = dinv[u3];
        float d4 = dinv[u4], d5 = dinv[u5], d6 = dinv[u6], d7 = dinv[u7];
        s0 += d0 * bf2f(a0.x) + d1 * bf2f(a1.x) + d2 * bf2f(a2.x) + d3 * bf2f(a3.x)
            + d4 * bf2f(a4.x) + d5 * bf2f(a5.x) + d6 * bf2f(a6.x) + d7 * bf2f(a7.x);
        s1 += d0 * bf2f(a0.y) + d1 * bf2f(a1.y) + d2 * bf2f(a2.y) + d3 * bf2f(a3.y)
            + d4 * bf2f(a4.y) + d5 * bf2f(a5.y) + d6 * bf2f(a6.y) + d7 * bf2f(a7.y);
        s2 += d0 * bf2f(a0.z) + d1 * bf2f(a1.z) + d2 * bf2f(a2.z) + d3 * bf2f(a3.z)
            + d4 * bf2f(a4.z) + d5 * bf2f(a5.z) + d6 * bf2f(a6.z) + d7 * bf2f(a7.z);
        s3 += d0 * bf2f(a0.w) + d1 * bf2f(a1.w) + d2 * bf2f(a2.w) + d3 * bf2f(a3.w)
            + d4 * bf2f(a4.w) + d5 * bf2f(a5.w) + d6 * bf2f(a6.w) + d7 * bf2f(a7.w);
    }
    float a = *aptr;
    float4 bb = *(const float4*)(bias + lane * 4);
    float o0 = dv * s0 + bb.x, o1 = dv * s1 + bb.y, o2 = dv * s2 + bb.z, o3 = dv * s3 + bb.w;
    o0 = o0 >= 0.f ? o0 : a * o0;
    o1 = o1 >= 0.f ? o1 : a * o1;
    o2 = o2 >= 0.f ? o2 : a * o2;
    o3 = o3 >= 0.f ? o3 : a * o3;
    ushort4 o; o.x = f2bf(o0); o.y = f2bf(o1); o.z = f2bf(o2); o.w = f2bf(o3);
    ((ushort4*)outb)[(size_t)v * 64 + lane] = o;
}

// ---------------- BN column stats (vectorized ushort4) ----------------
__global__ __launch_bounds__(256) void k_bnstats_v(const unsigned short* __restrict__ X, float* __restrict__ sums, int N) {
    int w = threadIdx.x >> 6, lane = threadIdx.x & 63;
    int c4 = lane * 4;
    float4 s = {0.f, 0.f, 0.f, 0.f}, q = {0.f, 0.f, 0.f, 0.f};
    int rstride = gridDim.x * 4;
    for (int r = blockIdx.x * 4 + w; r < N; r += rstride) {
        ushort4 x4 = ((const ushort4*)X)[(size_t)r * 64 + lane];
        float a = bf2f(x4.x), b = bf2f(x4.y), c = bf2f(x4.z), d = bf2f(x4.w);
        s.x += a; s.y += b; s.z += c; s.w += d;
        q.x += a * a; q.y += b * b; q.z += c * c; q.w += d * d;
    }
    atomicAdd(&sums[c4 + 0], s.x); atomicAdd(&sums[c4 + 1], s.y);
    atomicAdd(&sums[c4 + 2], s.z); atomicAdd(&sums[c4 + 3], s.w);
    atomicAdd(&sums[256 + c4 + 0], q.x); atomicAdd(&sums[256 + c4 + 1], q.y);
    atomicAdd(&sums[256 + c4 + 2], q.z); atomicAdd(&sums[256 + c4 + 3], q.w);
}

__global__ __launch_bounds__(256) void k_bnfinal(float* stats, const float* __restrict__ gamma,
                                                 const float* __restrict__ beta, float invN) {
    int c = threadIdx.x;
    float mu = stats[c] * invN;
    float var = stats[256 + c] * invN - mu * mu;
    float rstd = rsqrtf(var + 1e-5f);
    float sc = rstd * gamma[c];
    stats[512 + c] = sc;
    stats[768 + c] = beta[c] - mu * sc;
}

// ---------------- BN apply for z: f32 out + bf16 copy (no prelu) ----------------
__global__ __launch_bounds__(256) void k_bnapply_z(const unsigned short* __restrict__ in,
                                                   float* __restrict__ zout, unsigned short* __restrict__ zb,
                                                   const float* __restrict__ scale, const float* __restrict__ shift,
                                                   size_t n4) {
    size_t stride = (size_t)gridDim.x * blockDim.x;
    for (size_t i = (size_t)blockIdx.x * blockDim.x + threadIdx.x; i < n4; i += stride) {
        int c4 = (int)(i & 63) * 4;
        ushort4 x4 = ((const ushort4*)in)[i];
        float4 sc = *(const float4*)(scale + c4);
        float4 sh = *(const float4*)(shift + c4);
        float4 y;
        y.x = bf2f(x4.x) * sc.x + sh.x;
        y.y = bf2f(x4.y) * sc.y + sh.y;
        y.z = bf2f(x4.z) * sc.z + sh.z;
        y.w = bf2f(x4.w) * sc.w + sh.w;
        ((float4*)zout)[i] = y;
        ushort4 o; o.x = f2bf(y.x); o.y = f2bf(y.y); o.z = f2bf(y.z); o.w = f2bf(y.w);
        ((ushort4*)zb)[i] = o;
    }
}

// ---------------- BN apply for p: prelu, f32 out ----------------
__global__ __launch_bounds__(256) void k_bnapply_p(const unsigned short* __restrict__ in,
                                                   float* __restrict__ pout,
                                                   const float* __restrict__ scale, const float* __restrict__ shift,
                                                   const float* __restrict__ aptr, size_t n4) {
    size_t stride = (size_t)gridDim.x * blockDim.x;
    float a = *aptr;
    for (size_t i = (size_t)blockIdx.x * blockDim.x + threadIdx.x; i < n4; i += stride) {
        int c4 = (int)(i & 63) * 4;
        ushort4 x4 = ((const ushort4*)in)[i];
        float4 sc = *(const float4*)(scale + c4);
        float4 sh = *(const float4*)(shift + c4);
        float4 y;
        y.x = bf2f(x4.x) * sc.x + sh.x;
        y.y = bf2f(x4.y) * sc.y + sh.y;
        y.z = bf2f(x4.z) * sc.z + sh.z;
        y.w = bf2f(x4.w) * sc.w + sh.w;
        y.x = y.x >= 0.f ? y.x : a * y.x;
        y.y = y.y >= 0.f ? y.y : a * y.y;
        y.z = y.z >= 0.f ? y.z : a * y.z;
        y.w = y.w >= 0.f ? y.w : a * y.w;
        ((float4*)pout)[i] = y;
    }
}

extern "C" void kernel_launch(void* const* d_in, const int* in_sizes, int n_in,
                              void* d_out, int out_size, void* d_ws, size_t ws_size,
                              hipStream_t stream) {
    const float* x     = (const float*)d_in[0];
    const int*   ei    = (const int*)d_in[1];
    const float* W1    = (const float*)d_in[2];
    const float* b1    = (const float*)d_in[3];
    const float* W2    = (const float*)d_in[4];
    const float* b2    = (const float*)d_in[5];
    const float* aptr  = (const float*)d_in[6];
    const float* gamma = (const float*)d_in[7];
    const float* beta  = (const float*)d_in[8];
    const float* projW = (const float*)d_in[9];
    // d_in[10] = proj_b: cancels inside BN, unused
    const float* pgamma = (const float*)d_in[11];
    const float* pbeta  = (const float*)d_in[12];
    const float* a2ptr  = (const float*)d_in[13];

    int N = in_sizes[0] / 256;
    int E = in_sizes[1] / 2;
    const int* row = ei;
    const int* col = ei + E;

    float* out  = (float*)d_out;
    float* zout = out;
    float* pout = out + (size_t)N * 256;

    int nbkt = (N + NPB - 1) / NPB;

    // workspace layout: B0|B1|B2 bf16 [N,256], Wt, dinv[N+1], fillp, csr, stats, segcnt
    unsigned short* B0 = (unsigned short*)d_ws;
    unsigned short* B1 = B0 + (size_t)N * 256;
    unsigned short* B2 = B1 + (size_t)N * 256;
    unsigned short* Wt = B2 + (size_t)N * 256;
    float* dinv  = (float*)(Wt + 3 * 65536);
    int*   fillp = (int*)(dinv + N + 1);
    int*   csr   = fillp + N;
    float* stats = (float*)(csr + (size_t)N * CAP);
    int*   segcnt= (int*)(stats + 2048);
    unsigned* bins = (unsigned*)(segcnt + MAXBKT);   // nbkt*SEGBIG u32 (~7.2MB)

    int nb_binh = (E + CHUNK - 1) / CHUNK;
    dim3 ggrid((N + 127) / 128, 2);
    dim3 wgrid(8, 8);
    int  agrid = (N + 3) / 4;
    size_t n4 = (size_t)N * 64;

    // graph build + precasts
    k_zero <<<(2048 + 255) / 256, 256, 0, stream>>>(segcnt, nbkt, stats, dinv, N);
    k_binh <<<nb_binh, 256, 0, stream>>>(row, col, bins, segcnt, E, nbkt);
    k_csr  <<<nbkt, 256, 0, stream>>>(bins, segcnt, csr, fillp, dinv, N);
    k_castx<<<2048, 256, 0, stream>>>(x, B0, n4);
    k_wt   <<<wgrid, 256, 0, stream>>>(W1,    Wt);
    k_wt   <<<wgrid, 256, 0, stream>>>(W2,    Wt + 65536);
    k_wt   <<<wgrid, 256, 0, stream>>>(projW, Wt + 131072);

    // layer 1
    k_gemm_bf16<<<ggrid, 256, 0, stream>>>(B0, Wt, B1, N);
    k_agg_bf   <<<agrid, 256, 0, stream>>>(B1, B2, dinv, csr, fillp, b1, aptr, N);
    // layer 2
    k_gemm_bf16<<<ggrid, 256, 0, stream>>>(B2, Wt + 65536, B1, N);
    k_agg_bf   <<<agrid, 256, 0, stream>>>(B1, B0, dinv, csr, fillp, b2, aptr, N);
    // BN(z2) -> z (f32) + zb (bf16)
    k_bnstats_v<<<128, 256, 0, stream>>>(B0, stats, N);
    k_bnfinal  <<<1, 256, 0, stream>>>(stats, gamma, beta, 1.0f / (float)N);
    k_bnapply_z<<<2048, 256, 0, stream>>>(B0, zout, B2, stats + 512, stats + 768, n4);
    // projection head
    k_gemm_bf16<<<ggrid, 256, 0, stream>>>(B2, Wt + 131072, B1, N);
    k_bnstats_v<<<128, 256, 0, stream>>>(B1, stats + 1024, N);
    k_bnfinal  <<<1, 256, 0, stream>>>(stats + 1024, pgamma, pbeta, 1.0f / (float)N);
    k_bnapply_p<<<2048, 256, 0, stream>>>(B1, pout, stats + 1536, stats + 1792, a2ptr, n4);
}

// Round 9
// 677.337 us; speedup vs baseline: 1.1675x; 1.0075x over previous
//
#include <hip/hip_runtime.h>
#include <hip/hip_bf16.h>

// GCN (bf16): hs1 = dinv*(xb@W1) [prescaled in GEMM epilogue]; z1 = prelu(dv*(sum hs1)+b1)
//             hs2 = dinv*(z1@W2); z2 = prelu(dv*(sum hs2)+b2)
// z = BN(z2); p = prelu(BN2(z@projW))  [proj_b cancels in BN]; out = [z | p] (f32)
//
// R6->R7: GEMM C-tile staged in LDS -> coalesced 16B stores (was scalar 2B scatter);
// dinv folded into GEMM epilogue (agg loop = pure row sum); agg 16-deep MLP.

#define CAP 96          // max in-degree capacity (actual max deg ~60); multiple of 16
#define NPB 128         // nodes per bucket
#define CHUNK 4096      // edges per k_binh block
#define SEGBIG 4608     // entries per bucket segment (mean 4096 + 8 sigma)
#define MAXBKT 512      // supports N up to 65536

typedef __attribute__((ext_vector_type(8))) short short8;
typedef __attribute__((ext_vector_type(4))) float f32x4;

__device__ __forceinline__ float bf2f(unsigned short u) {
    union { unsigned int i; float f; } v; v.i = ((unsigned int)u) << 16; return v.f;
}
__device__ __forceinline__ unsigned short f2bf(float f) {
    __hip_bfloat16 h = __float2bfloat16(f);   // RNE
    return *reinterpret_cast<unsigned short*>(&h);
}

// ---------------- zero: segcnt, stats, dinv[N] sentinel ----------------
__global__ __launch_bounds__(256) void k_zero(int* segcnt, int nbkt, float* stats, float* dinv, int N) {
    int i = blockIdx.x * 256 + threadIdx.x;
    if (i < nbkt) segcnt[i] = 0;
    if (i < 2048) stats[i] = 0.0f;
    if (i == 0) dinv[N] = 0.0f;   // padding sentinel weight
}

// Sentinel rows: padded slots point at node N; hs row N is allocated and zeroed
// (k_zrow) so sentinel gathers read zeros and contribute nothing.
__global__ __launch_bounds__(256) void k_zrow(unsigned short* hs, int N) {
    ((ushort4*)hs)[(size_t)N * 64 + threadIdx.x % 64] = ushort4{0, 0, 0, 0};
}

// ---------------- phase 1: LDS-histogram binning by destination bucket ----------------
__global__ __launch_bounds__(256) void k_binh(const int* __restrict__ row, const int* __restrict__ col,
                                              unsigned* __restrict__ bins, int* __restrict__ segcnt,
                                              int E, int nbkt) {
    __shared__ int hist[MAXBKT];
    __shared__ int base[MAXBKT];
    int e0 = blockIdx.x * CHUNK;
    int eend = e0 + CHUNK; if (eend > E) eend = E;
    for (int b = threadIdx.x; b < nbkt; b += 256) hist[b] = 0;
    __syncthreads();
    for (int e = e0 + threadIdx.x; e < eend; e += 256)
        atomicAdd(&hist[col[e] >> 7], 1);
    __syncthreads();
    for (int b = threadIdx.x; b < nbkt; b += 256) {
        int h = hist[b];
        base[b] = h ? atomicAdd(&segcnt[b], h) : 0;
        hist[b] = 0;                       // reuse as running offset
    }
    __syncthreads();
    for (int e = e0 + threadIdx.x; e < eend; e += 256) {
        int v = col[e], r = row[e];
        int b = v >> 7;
        int p = base[b] + atomicAdd(&hist[b], 1);
        if (p < SEGBIG) bins[(size_t)b * SEGBIG + p] = ((unsigned)r << 7) | (unsigned)(v & (NPB - 1));
    }
}

// ---------------- phase 2: per-bucket CSR scatter + dinv + pad-to-16 ----------------
__global__ __launch_bounds__(256) void k_csr(const unsigned* __restrict__ bins, const int* __restrict__ segcnt,
                                             int* __restrict__ csr, int* __restrict__ fillp,
                                             float* __restrict__ dinv, int N) {
    __shared__ int cnt[NPB];
    int bkt = blockIdx.x;
    if (threadIdx.x < NPB) cnt[threadIdx.x] = 0;
    __syncthreads();
    int m = segcnt[bkt]; if (m > SEGBIG) m = SEGBIG;
    const unsigned* b = bins + (size_t)bkt * SEGBIG;
    for (int i = threadIdx.x; i < m; i += 256) {
        unsigned ent = b[i];
        int loc = (int)(ent & (NPB - 1));
        int r   = (int)(ent >> 7);
        int p = atomicAdd(&cnt[loc], 1);
        if (p < CAP) csr[(size_t)(bkt * NPB + loc) * CAP + p] = r;
    }
    __syncthreads();
    if (threadIdx.x < NPB) {
        int v = bkt * NPB + threadIdx.x;
        if (v < N) {
            int c = cnt[threadIdx.x];
            int real = c < CAP ? c : CAP;
            int pc = (real + 15) & ~15;           // pad to multiple of 16
            if (pc > CAP) pc = CAP;
            int* lst = csr + (size_t)v * CAP;
            for (int p = real; p < pc; ++p) lst[p] = N;   // sentinel: hs row N = 0
            fillp[v] = pc;
            dinv[v] = rsqrtf(1.0f + (float)c);    // +1 self loop
        }
    }
}

// ---------------- cast f32 -> bf16 (vectorized) ----------------
__global__ __launch_bounds__(256) void k_castx(const float* __restrict__ x, unsigned short* __restrict__ xb, size_t n4) {
    size_t stride = (size_t)gridDim.x * blockDim.x;
    for (size_t i = (size_t)blockIdx.x * blockDim.x + threadIdx.x; i < n4; i += stride) {
        float4 v = ((const float4*)x)[i];
        ushort4 o; o.x = f2bf(v.x); o.y = f2bf(v.y); o.z = f2bf(v.z); o.w = f2bf(v.w);
        ((ushort4*)xb)[i] = o;
    }
}

// ---------------- W [256,256] f32 -> Wt [n][k] bf16 (transpose + cast) ----------------
__global__ __launch_bounds__(256) void k_wt(const float* __restrict__ W, unsigned short* __restrict__ Wt) {
    __shared__ float t[32][33];
    int bx = blockIdx.x * 32, by = blockIdx.y * 32;
    int x = threadIdx.x & 31, y = threadIdx.x >> 5;   // 32x8
#pragma unroll
    for (int i = 0; i < 32; i += 8)
        t[y + i][x] = W[(size_t)(by + y + i) * 256 + bx + x];
    __syncthreads();
#pragma unroll
    for (int i = 0; i < 32; i += 8)
        Wt[(size_t)(bx + y + i) * 256 + by + x] = f2bf(t[x][y + i]);  // Wt[n][k] = W[k][n]
}

// ---------------- bf16 MFMA GEMM + LDS-staged coalesced epilogue ----------------
// C[M,256] = A[M,256] @ B (Bt[n][k]); optional per-row dinv prescale (use_scale).
__global__ __launch_bounds__(256) void k_gemm_bf16(const unsigned short* __restrict__ A,
                                                   const unsigned short* __restrict__ Bt,
                                                   unsigned short* __restrict__ C,
                                                   const float* __restrict__ dinv,
                                                   int use_scale, int M) {
    __shared__ unsigned short buf[16384];     // As=buf[0:8192), Bs=buf[8192:16384); C-stage reuses all 32KB
    unsigned short* As = buf;
    unsigned short* Bs = buf + 8192;
    int tid  = threadIdx.x;
    int lane = tid & 63, wid = tid >> 6;
    int wr = wid >> 1, wc = wid & 1;
    int row0 = blockIdx.x * 128;
    int col0 = blockIdx.y * 128;

    f32x4 acc[4][4];
#pragma unroll
    for (int m = 0; m < 4; ++m)
#pragma unroll
        for (int n = 0; n < 4; ++n) acc[m][n] = f32x4{0.f, 0.f, 0.f, 0.f};

    int srow = lane >> 3;          // 0..7
    int sk   = (lane & 7) * 8;     // 0,8,...,56

    for (int k0 = 0; k0 < 256; k0 += 64) {
#pragma unroll
        for (int i = 0; i < 4; ++i) {
            int u = i * 4 + wid;                       // load unit 0..15, wave-uniform
            int arow = row0 + u * 8 + srow;
            if (arow >= M) arow = M - 1;               // per-lane source clamp (dest stays linear)
            const unsigned short* ga = A  + (size_t)arow * 256 + k0 + sk;
            const unsigned short* gb = Bt + (size_t)(col0 + u * 8 + srow) * 256 + k0 + sk;
            __builtin_amdgcn_global_load_lds((const __attribute__((address_space(1))) void*)ga,
                (__attribute__((address_space(3))) void*)(As + u * 512), 16, 0, 0);
            __builtin_amdgcn_global_load_lds((const __attribute__((address_space(1))) void*)gb,
                (__attribute__((address_space(3))) void*)(Bs + u * 512), 16, 0, 0);
        }
        __syncthreads();
#pragma unroll
        for (int kk = 0; kk < 64; kk += 32) {
            short8 a[4], b[4];
#pragma unroll
            for (int m = 0; m < 4; ++m)
                a[m] = *(const short8*)(As + (wr * 64 + m * 16 + (lane & 15)) * 64 + kk + (lane >> 4) * 8);
#pragma unroll
            for (int n = 0; n < 4; ++n)
                b[n] = *(const short8*)(Bs + (wc * 64 + n * 16 + (lane & 15)) * 64 + kk + (lane >> 4) * 8);
#pragma unroll
            for (int m = 0; m < 4; ++m)
#pragma unroll
                for (int n = 0; n < 4; ++n)
                    acc[m][n] = __builtin_amdgcn_mfma_f32_16x16x32_bf16(a[m], b[n], acc[m][n], 0, 0, 0);
        }
        __syncthreads();
    }

    // stage C tile (bf16) into LDS; MFMA C/D layout: col=lane&15, row=(lane>>4)*4+r
#pragma unroll
    for (int m = 0; m < 4; ++m)
#pragma unroll
        for (int r = 0; r < 4; ++r) {
            int lr = wr * 64 + m * 16 + (lane >> 4) * 4 + r;
#pragma unroll
            for (int n = 0; n < 4; ++n)
                buf[lr * 128 + wc * 64 + n * 16 + (lane & 15)] = f2bf(acc[m][n][r]);
        }
    __syncthreads();
    // coalesced store: 2048 chunks of 16B; optional per-row dinv prescale
#pragma unroll
    for (int j = 0; j < 8; ++j) {
        int c = j * 256 + tid;
        int r = c >> 4, cc = c & 15;
        int grow = row0 + r;
        if (grow < M) {
            short8 v = *(const short8*)(buf + r * 128 + cc * 8);
            if (use_scale) {
                float d = dinv[grow];
                short8 o;
#pragma unroll
                for (int t = 0; t < 8; ++t)
                    o[t] = (short)f2bf(bf2f((unsigned short)v[t]) * d);
                v = o;
            }
            *(short8*)(C + (size_t)grow * 256 + col0 + cc * 8) = v;
        }
    }
}

// ---------------- aggregation: pure 16-wide row sum (hs prescaled) ----------------
// out[v] = prelu(dv * (sum_{u in lst} hs[u] + hs[v]) + b)   [sentinel rows = 0]
__global__ __launch_bounds__(256) void k_agg_bf(const unsigned short* __restrict__ hs,
                                                unsigned short* __restrict__ outb,
                                                const float* __restrict__ dinv, const int* __restrict__ csr,
                                                const int* __restrict__ fillp, const float* __restrict__ bias,
                                                const float* __restrict__ aptr, int N) {
    int wv = threadIdx.x >> 6, lane = threadIdx.x & 63;   // one node per wave, 4 ch/lane
    int v = blockIdx.x * 4 + wv;
    if (v >= N) return;
    const ushort4* h4 = (const ushort4*)hs;
    float dv = dinv[v];
    ushort4 hv = h4[(size_t)v * 64 + lane];
    float s0 = bf2f(hv.x), s1 = bf2f(hv.y), s2 = bf2f(hv.z), s3 = bf2f(hv.w);
    int n = fillp[v];                      // multiple of 16 (sentinel-padded)
    const int* lst = csr + (size_t)v * CAP;
    for (int i = 0; i < n; i += 16) {
        int u[16];
        ushort4 a[16];
#pragma unroll
        for (int t = 0; t < 16; ++t) u[t] = lst[i + t];
#pragma unroll
        for (int t = 0; t < 16; ++t) a[t] = h4[(size_t)u[t] * 64 + lane];
#pragma unroll
        for (int t = 0; t < 16; ++t) {
            s0 += bf2f(a[t].x); s1 += bf2f(a[t].y);
            s2 += bf2f(a[t].z); s3 += bf2f(a[t].w);
        }
    }
    float al = *aptr;
    float4 bb = *(const float4*)(bias + lane * 4);
    float o0 = dv * s0 + bb.x, o1 = dv * s1 + bb.y, o2 = dv * s2 + bb.z, o3 = dv * s3 + bb.w;
    o0 = o0 >= 0.f ? o0 : al * o0;
    o1 = o1 >= 0.f ? o1 : al * o1;
    o2 = o2 >= 0.f ? o2 : al * o2;
    o3 = o3 >= 0.f ? o3 : al * o3;
    ushort4 o; o.x = f2bf(o0); o.y = f2bf(o1); o.z = f2bf(o2); o.w = f2bf(o3);
    ((ushort4*)outb)[(size_t)v * 64 + lane] = o;
}

// ---------------- BN column stats (vectorized ushort4) ----------------
__global__ __launch_bounds__(256) void k_bnstats_v(const unsigned short* __restrict__ X, float* __restrict__ sums, int N) {
    int w = threadIdx.x >> 6, lane = threadIdx.x & 63;
    int c4 = lane * 4;
    float4 s = {0.f, 0.f, 0.f, 0.f}, q = {0.f, 0.f, 0.f, 0.f};
    int rstride = gridDim.x * 4;
    for (int r = blockIdx.x * 4 + w; r < N; r += rstride) {
        ushort4 x4 = ((const ushort4*)X)[(size_t)r * 64 + lane];
        float a = bf2f(x4.x), b = bf2f(x4.y), c = bf2f(x4.z), d = bf2f(x4.w);
        s.x += a; s.y += b; s.z += c; s.w += d;
        q.x += a * a; q.y += b * b; q.z += c * c; q.w += d * d;
    }
    atomicAdd(&sums[c4 + 0], s.x); atomicAdd(&sums[c4 + 1], s.y);
    atomicAdd(&sums[c4 + 2], s.z); atomicAdd(&sums[c4 + 3], s.w);
    atomicAdd(&sums[256 + c4 + 0], q.x); atomicAdd(&sums[256 + c4 + 1], q.y);
    atomicAdd(&sums[256 + c4 + 2], q.z); atomicAdd(&sums[256 + c4 + 3], q.w);
}

__global__ __launch_bounds__(256) void k_bnfinal(float* stats, const float* __restrict__ gamma,
                                                 const float* __restrict__ beta, float invN) {
    int c = threadIdx.x;
    float mu = stats[c] * invN;
    float var = stats[256 + c] * invN - mu * mu;
    float rstd = rsqrtf(var + 1e-5f);
    float sc = rstd * gamma[c];
    stats[512 + c] = sc;
    stats[768 + c] = beta[c] - mu * sc;
}

// ---------------- BN apply for z: f32 out + bf16 copy (no prelu) ----------------
__global__ __launch_bounds__(256) void k_bnapply_z(const unsigned short* __restrict__ in,
                                                   float* __restrict__ zout, unsigned short* __restrict__ zb,
                                                   const float* __restrict__ scale, const float* __restrict__ shift,
                                                   size_t n4) {
    size_t stride = (size_t)gridDim.x * blockDim.x;
    for (size_t i = (size_t)blockIdx.x * blockDim.x + threadIdx.x; i < n4; i += stride) {
        int c4 = (int)(i & 63) * 4;
        ushort4 x4 = ((const ushort4*)in)[i];
        float4 sc = *(const float4*)(scale + c4);
        float4 sh = *(const float4*)(shift + c4);
        float4 y;
        y.x = bf2f(x4.x) * sc.x + sh.x;
        y.y = bf2f(x4.y) * sc.y + sh.y;
        y.z = bf2f(x4.z) * sc.z + sh.z;
        y.w = bf2f(x4.w) * sc.w + sh.w;
        ((float4*)zout)[i] = y;
        ushort4 o; o.x = f2bf(y.x); o.y = f2bf(y.y); o.z = f2bf(y.z); o.w = f2bf(y.w);
        ((ushort4*)zb)[i] = o;
    }
}

// ---------------- BN apply for p: prelu, f32 out ----------------
__global__ __launch_bounds__(256) void k_bnapply_p(const unsigned short* __restrict__ in,
                                                   float* __restrict__ pout,
                                                   const float* __restrict__ scale, const float* __restrict__ shift,
                                                   const float* __restrict__ aptr, size_t n4) {
    size_t stride = (size_t)gridDim.x * blockDim.x;
    float a = *aptr;
    for (size_t i = (size_t)blockIdx.x * blockDim.x + threadIdx.x; i < n4; i += stride) {
        int c4 = (int)(i & 63) * 4;
        ushort4 x4 = ((const ushort4*)in)[i];
        float4 sc = *(const float4*)(scale + c4);
        float4 sh = *(const float4*)(shift + c4);
        float4 y;
        y.x = bf2f(x4.x) * sc.x + sh.x;
        y.y = bf2f(x4.y) * sc.y + sh.y;
        y.z = bf2f(x4.z) * sc.z + sh.z;
        y.w = bf2f(x4.w) * sc.w + sh.w;
        y.x = y.x >= 0.f ? y.x : a * y.x;
        y.y = y.y >= 0.f ? y.y : a * y.y;
        y.z = y.z >= 0.f ? y.z : a * y.z;
        y.w = y.w >= 0.f ? y.w : a * y.w;
        ((float4*)pout)[i] = y;
    }
}

extern "C" void kernel_launch(void* const* d_in, const int* in_sizes, int n_in,
                              void* d_out, int out_size, void* d_ws, size_t ws_size,
                              hipStream_t stream) {
    const float* x     = (const float*)d_in[0];
    const int*   ei    = (const int*)d_in[1];
    const float* W1    = (const float*)d_in[2];
    const float* b1    = (const float*)d_in[3];
    const float* W2    = (const float*)d_in[4];
    const float* b2    = (const float*)d_in[5];
    const float* aptr  = (const float*)d_in[6];
    const float* gamma = (const float*)d_in[7];
    const float* beta  = (const float*)d_in[8];
    const float* projW = (const float*)d_in[9];
    // d_in[10] = proj_b: cancels inside BN, unused
    const float* pgamma = (const float*)d_in[11];
    const float* pbeta  = (const float*)d_in[12];
    const float* a2ptr  = (const float*)d_in[13];

    int N = in_sizes[0] / 256;
    int E = in_sizes[1] / 2;
    const int* row = ei;
    const int* col = ei + E;

    float* out  = (float*)d_out;
    float* zout = out;
    float* pout = out + (size_t)N * 256;

    int nbkt = (N + NPB - 1) / NPB;

    // workspace: B0|B1|B2 bf16 [(N+1),256] (row N = zero row for sentinels), Wt, graph, stats
    size_t rowsz = (size_t)(N + 1) * 256;
    unsigned short* B0 = (unsigned short*)d_ws;
    unsigned short* B1 = B0 + rowsz;
    unsigned short* B2 = B1 + rowsz;
    unsigned short* Wt = B2 + rowsz;
    float* dinv  = (float*)(Wt + 3 * 65536);
    int*   fillp = (int*)(dinv + N + 1);
    int*   csr   = fillp + N;
    float* stats = (float*)(csr + (size_t)N * CAP);
    int*   segcnt= (int*)(stats + 2048);
    unsigned* bins = (unsigned*)(segcnt + MAXBKT);   // nbkt*SEGBIG u32 (~7.2MB)

    int nb_binh = (E + CHUNK - 1) / CHUNK;
    dim3 ggrid((N + 127) / 128, 2);
    dim3 wgrid(8, 8);
    int  agrid = (N + 3) / 4;
    size_t n4 = (size_t)N * 64;

    // graph build + precasts
    k_zero <<<8, 256, 0, stream>>>(segcnt, nbkt, stats, dinv, N);
    k_zrow <<<1, 64, 0, stream>>>(B1, N);            // zero sentinel row of h-buffer
    k_binh <<<nb_binh, 256, 0, stream>>>(row, col, bins, segcnt, E, nbkt);
    k_csr  <<<nbkt, 256, 0, stream>>>(bins, segcnt, csr, fillp, dinv, N);
    k_castx<<<2048, 256, 0, stream>>>(x, B0, n4);
    k_wt   <<<wgrid, 256, 0, stream>>>(W1,    Wt);
    k_wt   <<<wgrid, 256, 0, stream>>>(W2,    Wt + 65536);
    k_wt   <<<wgrid, 256, 0, stream>>>(projW, Wt + 131072);

    // layer 1: hs1 = dinv*(xb@W1) -> B1 ; z1 -> B2
    k_gemm_bf16<<<ggrid, 256, 0, stream>>>(B0, Wt, B1, dinv, 1, N);
    k_agg_bf   <<<agrid, 256, 0, stream>>>(B1, B2, dinv, csr, fillp, b1, aptr, N);
    // layer 2: hs2 = dinv*(z1@W2) -> B1 ; z2 -> B0   (B1 row N still zero: GEMM writes rows<N only)
    k_zrow <<<1, 64, 0, stream>>>(B1, N);
    k_gemm_bf16<<<ggrid, 256, 0, stream>>>(B2, Wt + 65536, B1, dinv, 1, N);
    k_agg_bf   <<<agrid, 256, 0, stream>>>(B1, B0, dinv, csr, fillp, b2, aptr, N);
    // BN(z2) -> z (f32) + zb (bf16)
    k_bnstats_v<<<128, 256, 0, stream>>>(B0, stats, N);
    k_bnfinal  <<<1, 256, 0, stream>>>(stats, gamma, beta, 1.0f / (float)N);
    k_bnapply_z<<<2048, 256, 0, stream>>>(B0, zout, B2, stats + 512, stats + 768, n4);
    // projection head: praw = zb@projW (no prescale)
    k_gemm_bf16<<<ggrid, 256, 0, stream>>>(B2, Wt + 131072, B1, dinv, 0, N);
    k_bnstats_v<<<128, 256, 0, stream>>>(B1, stats + 1024, N);
    k_bnfinal  <<<1, 256, 0, stream>>>(stats + 1024, pgamma, pbeta, 1.0f / (float)N);
    k_bnapply_p<<<2048, 256, 0, stream>>>(B1, pout, stats + 1536, stats + 1792, a2ptr, n4);
}